// Round 1
// baseline (928.780 us; speedup 1.0000x reference)
//
#include <hip/hip_runtime.h>

#define N_EP     4096     // 2048 lines * 2 endpoints
#define NLINES   2048
#define KPTS     2048
#define CCH      256
#define HC_      128
#define WC_      128
#define MAXNBR   16
#define NPTS_ALL 6144     // N_EP + KPTS

// ---- output chunk offsets (floats) ----
#define O_PTS  0          // all_points (1,6144,2)       12288
#define O_SC   12288      // all_scores (1,6144)          6144
#define O_DESC 18432      // all_descs (1,256,6144)    1572864
#define O_NL   1591296    // new_lines (1,2048,2,2)       8192
#define O_LJI  1599488    // lines_junc_idx (1,2048,2)    4096
#define O_LS   1603584    // ls (1,2048)                  2048

// ---- ws offsets (4-byte words) ----
#define W_LS   0          // float[2048]
#define W_DEG  2048       // int[4096]
#define W_NBR  6144       // int[4096*16]
#define W_CL   71680      // int[4096]
#define W_CNT  75776      // float[4096]
#define W_SX   79872      // float[4096]
#define W_SY   83968      // float[4096]
#define W_SS   88064      // float[4096]
#define W_JUNC 92160      // float[8192] (x,y interleaved)

// K1: ls = line_scores / (1e-8 + max(line_scores))
__global__ void k_ls(const float* __restrict__ lsc, float* __restrict__ ws_ls,
                     float* __restrict__ out_ls) {
    __shared__ float red[256];
    int t = threadIdx.x;
    float m = -1e30f;
    for (int i = t; i < NLINES; i += 256) m = fmaxf(m, lsc[i]);
    red[t] = m; __syncthreads();
    for (int s = 128; s > 0; s >>= 1) {
        if (t < s) red[t] = fmaxf(red[t], red[t + s]);
        __syncthreads();
    }
    float denom = 1e-8f + red[0];
    for (int i = t; i < NLINES; i += 256) {
        float v = lsc[i] / denom;
        ws_ls[i] = v;
        out_ls[i] = v;
    }
}

// K2: neighbor lists of the eps<=3 ball graph over endpoints
__global__ void k_nbr(const float* __restrict__ ep, int* __restrict__ deg,
                      int* __restrict__ nbr) {
    int i = blockIdx.x * blockDim.x + threadIdx.x;
    if (i >= N_EP) return;
    float px = ep[2 * i], py = ep[2 * i + 1];
    int d = 0;
    for (int j = 0; j < N_EP; j++) {
        if (j == i) continue;
        float dx = px - ep[2 * j];
        float dy = py - ep[2 * j + 1];
        if (dx * dx + dy * dy <= 9.0f) {
            if (d < MAXNBR) nbr[i * MAXNBR + d] = j;
            d++;
        }
    }
    deg[i] = min(d, MAXNBR);
}

// K3: connected-component min-label + dense rank + segment sums
__global__ __launch_bounds__(1024) void k_cluster(
    const float* __restrict__ ep, const int* __restrict__ deg,
    const int* __restrict__ nbr, const float* __restrict__ ws_ls,
    int* __restrict__ ws_cl, float* __restrict__ cnt, float* __restrict__ sx,
    float* __restrict__ sy, float* __restrict__ ss, float* __restrict__ out_lji) {
    __shared__ int lab[N_EP];
    __shared__ int rnk[N_EP];
    __shared__ int tsum[1024];
    __shared__ int changed;
    int t = threadIdx.x;
    for (int i = t; i < N_EP; i += 1024) {
        cnt[i] = 0.f; sx[i] = 0.f; sy[i] = 0.f; ss[i] = 0.f;
        lab[i] = i;
    }
    // min-label propagation with pointer jumping; fixed point = per-component min index
    for (int it = 0; it < 64; ++it) {
        __syncthreads();
        if (t == 0) changed = 0;
        __syncthreads();
        int f = 0;
        for (int i = t; i < N_EP; i += 1024) {
            int m = lab[i];
            int dg = deg[i];
            const int* nb = nbr + i * MAXNBR;
            for (int q = 0; q < dg; q++) m = min(m, lab[nb[q]]);
            m = min(m, lab[m]);       // pointer jump (lab[k] <= k invariant)
            if (m < lab[i]) { lab[i] = m; f = 1; }
        }
        if (f) atomicOr(&changed, 1);
        __syncthreads();
        if (changed == 0) break;
    }
    __syncthreads();
    // dense rank of root indices (exclusive prefix sum of presence bitmap)
    for (int i = t; i < N_EP; i += 1024) rnk[i] = 0;
    __syncthreads();
    for (int i = t; i < N_EP; i += 1024) rnk[lab[i]] = 1;
    __syncthreads();
    int base = t * 4;
    int a0 = rnk[base], a1 = rnk[base + 1], a2 = rnk[base + 2], a3 = rnk[base + 3];
    int s = a0 + a1 + a2 + a3;
    tsum[t] = s; __syncthreads();
    for (int off = 1; off < 1024; off <<= 1) {
        int v = tsum[t];
        int u = (t >= off) ? tsum[t - off] : 0;
        __syncthreads();
        tsum[t] = v + u;
        __syncthreads();
    }
    int excl = tsum[t] - s;
    rnk[base] = excl;
    rnk[base + 1] = excl + a0;
    rnk[base + 2] = excl + a0 + a1;
    rnk[base + 3] = excl + a0 + a1 + a2;
    __syncthreads();
    for (int i = t; i < N_EP; i += 1024) {
        int c = rnk[lab[i]];
        ws_cl[i] = c;
        out_lji[i] = (float)c;
        float px = ep[2 * i], py = ep[2 * i + 1];
        atomicAdd(&cnt[c], 1.f);
        atomicAdd(&sx[c], px);
        atomicAdd(&sy[c], py);
        atomicAdd(&ss[c], ws_ls[i >> 1]);
    }
}

// K4: junction positions/scores = segment mean
__global__ void k_junc(const float* __restrict__ cnt, const float* __restrict__ sx,
                       const float* __restrict__ sy, const float* __restrict__ ss,
                       float* __restrict__ junc, float* __restrict__ out_pts,
                       float* __restrict__ out_sc) {
    int j = blockIdx.x * 256 + threadIdx.x;
    if (j >= N_EP) return;
    float c = fmaxf(cnt[j], 1.f);
    float jx = sx[j] / c, jy = sy[j] / c;
    junc[2 * j] = jx; junc[2 * j + 1] = jy;
    out_pts[2 * j] = jx; out_pts[2 * j + 1] = jy;
    out_sc[j] = ss[j] / c;
}

// K5: new_lines = junctions[clusters]
__global__ void k_newlines(const int* __restrict__ cl, const float* __restrict__ junc,
                           float* __restrict__ out_nl) {
    int e = blockIdx.x * 256 + threadIdx.x;
    if (e >= N_EP) return;
    int c = cl[e];
    out_nl[2 * e] = junc[2 * c];
    out_nl[2 * e + 1] = junc[2 * c + 1];
}

// K6: keypoint suppression near endpoints + masked kp/score writes
__global__ void k_kp(const float* __restrict__ ep, const float* __restrict__ kpts,
                     const float* __restrict__ ksc, int* __restrict__ keep_ws,
                     float* __restrict__ out_pts, float* __restrict__ out_sc) {
    int k = blockIdx.x * 256 + threadIdx.x;
    if (k >= KPTS) return;
    float kx = kpts[2 * k], ky = kpts[2 * k + 1];
    int keep = 1;
    for (int j = 0; j < N_EP; j++) {
        float dx = kx - ep[2 * j];
        float dy = ky - ep[2 * j + 1];
        if (dx * dx + dy * dy < 16.0f) { keep = 0; break; }
    }
    keep_ws[k] = keep;
    out_pts[2 * (N_EP + k)] = keep ? kx : 0.f;
    out_pts[2 * (N_EP + k) + 1] = keep ? ky : 0.f;
    out_sc[N_EP + k] = keep ? ksc[k] : 0.f;
}

// K7: bilinear sample + L2-normalize junction descriptors. block=junction, thread=channel
__global__ __launch_bounds__(256) void k_sample(const float* __restrict__ ad,
                                                const float* __restrict__ junc,
                                                float* __restrict__ out_desc) {
    int m = blockIdx.x;
    int c = threadIdx.x;
    float px = junc[2 * m], py = junc[2 * m + 1];
    float gx = (px - 4.0f + 0.5f) / 1019.5f * 2.f - 1.f;
    float gy = (py - 4.0f + 0.5f) / 1019.5f * 2.f - 1.f;
    float x = (gx + 1.f) * 0.5f * (WC_ - 1);
    float y = (gy + 1.f) * 0.5f * (HC_ - 1);
    float x0f = fminf(fmaxf(floorf(x), 0.f), WC_ - 1);
    float y0f = fminf(fmaxf(floorf(y), 0.f), HC_ - 1);
    float x1f = fminf(x0f + 1.f, WC_ - 1);
    float y1f = fminf(y0f + 1.f, HC_ - 1);
    float wx = x - x0f, wy = y - y0f;
    int x0 = (int)x0f, x1 = (int)x1f, y0 = (int)y0f, y1 = (int)y1f;
    const float* dch = ad + c * (HC_ * WC_);
    float v = dch[y0 * WC_ + x0] * (1.f - wx) * (1.f - wy)
            + dch[y0 * WC_ + x1] * wx * (1.f - wy)
            + dch[y1 * WC_ + x0] * (1.f - wx) * wy
            + dch[y1 * WC_ + x1] * wx * wy;
    float sq = v * v;
    for (int off = 32; off > 0; off >>= 1) sq += __shfl_down(sq, off);
    __shared__ float wsum[4];
    if ((c & 63) == 0) wsum[c >> 6] = sq;
    __syncthreads();
    float tot = wsum[0] + wsum[1] + wsum[2] + wsum[3];
    float inv = 1.f / fmaxf(sqrtf(tot), 1e-12f);
    out_desc[c * NPTS_ALL + m] = v * inv;
}

// K8: masked copy of keypoint descriptors into concatenated output
__global__ void k_kdesc(const float* __restrict__ desc, const int* __restrict__ keep,
                        float* __restrict__ out_desc) {
    int idx = blockIdx.x * 256 + threadIdx.x;
    if (idx >= CCH * KPTS) return;
    int c = idx >> 11, k = idx & 2047;
    out_desc[c * NPTS_ALL + N_EP + k] = keep[k] ? desc[idx] : 0.f;
}

extern "C" void kernel_launch(void* const* d_in, const int* in_sizes, int n_in,
                              void* d_out, int out_size, void* d_ws, size_t ws_size,
                              hipStream_t stream) {
    const float* lines    = (const float*)d_in[0];   // (1,2048,2,2) == endpoints (4096,2)
    const float* lscores  = (const float*)d_in[1];   // (1,2048)
    const float* kpts     = (const float*)d_in[2];   // (1,2048,2)
    const float* kscores  = (const float*)d_in[3];   // (1,2048)
    const float* descs    = (const float*)d_in[4];   // (1,256,2048)
    const float* alldesc  = (const float*)d_in[5];   // (1,256,128,128)
    float* out = (float*)d_out;

    float* wf = (float*)d_ws;
    int*   wi = (int*)d_ws;

    float* ws_ls  = wf + W_LS;
    int*   deg    = wi + W_DEG;
    int*   nbr    = wi + W_NBR;
    int*   ws_cl  = wi + W_CL;
    float* cnt    = wf + W_CNT;
    float* sx     = wf + W_SX;
    float* sy     = wf + W_SY;
    float* ss     = wf + W_SS;
    float* junc   = wf + W_JUNC;

    k_ls<<<1, 256, 0, stream>>>(lscores, ws_ls, out + O_LS);
    k_nbr<<<N_EP / 256, 256, 0, stream>>>(lines, deg, nbr);
    k_cluster<<<1, 1024, 0, stream>>>(lines, deg, nbr, ws_ls, ws_cl, cnt, sx, sy, ss,
                                      out + O_LJI);
    k_junc<<<N_EP / 256, 256, 0, stream>>>(cnt, sx, sy, ss, junc, out + O_PTS,
                                           out + O_SC);
    k_newlines<<<N_EP / 256, 256, 0, stream>>>(ws_cl, junc, out + O_NL);
    k_kp<<<KPTS / 256, 256, 0, stream>>>(lines, kpts, kscores, wi + W_CL + N_EP * 2,
                                         out + O_PTS, out + O_SC);
    // keep_ws actually needs its own slot; reuse region after junc
    int* keep = wi + W_JUNC + N_EP * 2;  // float[8192] junc then int[2048] keep
    k_kp<<<KPTS / 256, 256, 0, stream>>>(lines, kpts, kscores, keep,
                                         out + O_PTS, out + O_SC);
    k_sample<<<N_EP, 256, 0, stream>>>(alldesc, junc, out + O_DESC);
    k_kdesc<<<(CCH * KPTS) / 256, 256, 0, stream>>>(descs, keep, out + O_DESC);
}

// Round 2
// 89.491 us; speedup vs baseline: 10.3784x; 10.3784x over previous
//
#include <hip/hip_runtime.h>

#define N_EP     4096     // 2048 lines * 2 endpoints
#define NLINES   2048
#define KPTS     2048
#define CCH      256
#define HC_      128
#define WC_      128
#define MAXNBR   16
#define NPTS_ALL 6144     // N_EP + KPTS

// ---- output chunk offsets (floats) ----
#define O_PTS  0          // all_points (1,6144,2)       12288
#define O_SC   12288      // all_scores (1,6144)          6144
#define O_DESC 18432      // all_descs (1,256,6144)    1572864
#define O_NL   1591296    // new_lines (1,2048,2,2)       8192
#define O_LJI  1599488    // lines_junc_idx (1,2048,2)    4096
#define O_LS   1603584    // ls (1,2048)                  2048

// ---- ws offsets (4-byte words) ----
#define W_LS   0          // float[2048]
#define W_DEG  2048       // int[4096]
#define W_NBR  6144       // int[4096*16]
#define W_CL   71680      // int[4096]
#define W_CNT  75776      // float[4096]
#define W_SX   79872      // float[4096]
#define W_SY   83968      // float[4096]
#define W_SS   88064      // float[4096]
#define W_JUNC 92160      // float[8192] (x,y interleaved)
#define W_KEEP 100352     // int[2048]

// K1: ls = line_scores / (1e-8 + max(line_scores))
__global__ void k_ls(const float* __restrict__ lsc, float* __restrict__ ws_ls,
                     float* __restrict__ out_ls) {
    __shared__ float red[256];
    int t = threadIdx.x;
    float m = -1e30f;
    for (int i = t; i < NLINES; i += 256) m = fmaxf(m, lsc[i]);
    red[t] = m; __syncthreads();
    for (int s = 128; s > 0; s >>= 1) {
        if (t < s) red[t] = fmaxf(red[t], red[t + s]);
        __syncthreads();
    }
    float denom = 1e-8f + red[0];
    for (int i = t; i < NLINES; i += 256) {
        float v = lsc[i] / denom;
        ws_ls[i] = v;
        out_ls[i] = v;
    }
}

// K2: neighbor lists of the eps<=3 ball graph. One BLOCK per point i;
// 256 threads split the 4096-candidate scan. Order in nbr[] is arbitrary
// (atomic append) — min-label propagation is order-invariant.
__global__ __launch_bounds__(256) void k_nbr(const float2* __restrict__ ep,
                                             int* __restrict__ deg,
                                             int* __restrict__ nbr) {
    __shared__ int cnt_s;
    int i = blockIdx.x;
    if (threadIdx.x == 0) cnt_s = 0;
    __syncthreads();
    float2 p = ep[i];
    for (int j = threadIdx.x; j < N_EP; j += 256) {
        if (j == i) continue;
        float2 q = ep[j];
        float dx = p.x - q.x, dy = p.y - q.y;
        if (dx * dx + dy * dy <= 9.0f) {
            int s = atomicAdd(&cnt_s, 1);
            if (s < MAXNBR) nbr[i * MAXNBR + s] = j;
        }
    }
    __syncthreads();
    if (threadIdx.x == 0) deg[i] = min(cnt_s, MAXNBR);
}

// K3: connected-component min-label + dense rank + segment sums
__global__ __launch_bounds__(1024) void k_cluster(
    const float2* __restrict__ ep, const int* __restrict__ deg,
    const int* __restrict__ nbr, const float* __restrict__ ws_ls,
    int* __restrict__ ws_cl, float* __restrict__ cnt, float* __restrict__ sx,
    float* __restrict__ sy, float* __restrict__ ss, float* __restrict__ out_lji) {
    __shared__ int lab[N_EP];
    __shared__ int rnk[N_EP];
    __shared__ int tsum[1024];
    __shared__ int changed;
    int t = threadIdx.x;
    for (int i = t; i < N_EP; i += 1024) {
        cnt[i] = 0.f; sx[i] = 0.f; sy[i] = 0.f; ss[i] = 0.f;
        lab[i] = i;
    }
    // min-label propagation with pointer jumping; fixed point = per-component min index
    for (int it = 0; it < 64; ++it) {
        __syncthreads();
        if (t == 0) changed = 0;
        __syncthreads();
        int f = 0;
        for (int i = t; i < N_EP; i += 1024) {
            int m = lab[i];
            int dg = deg[i];
            const int* nb = nbr + i * MAXNBR;
            for (int q = 0; q < dg; q++) m = min(m, lab[nb[q]]);
            m = min(m, lab[m]);       // pointer jump (lab[k] <= k invariant)
            if (m < lab[i]) { lab[i] = m; f = 1; }
        }
        if (f) atomicOr(&changed, 1);
        __syncthreads();
        if (changed == 0) break;
    }
    __syncthreads();
    // dense rank of root indices (exclusive prefix sum of presence bitmap)
    for (int i = t; i < N_EP; i += 1024) rnk[i] = 0;
    __syncthreads();
    for (int i = t; i < N_EP; i += 1024) rnk[lab[i]] = 1;
    __syncthreads();
    int base = t * 4;
    int a0 = rnk[base], a1 = rnk[base + 1], a2 = rnk[base + 2], a3 = rnk[base + 3];
    int s = a0 + a1 + a2 + a3;
    tsum[t] = s; __syncthreads();
    for (int off = 1; off < 1024; off <<= 1) {
        int v = tsum[t];
        int u = (t >= off) ? tsum[t - off] : 0;
        __syncthreads();
        tsum[t] = v + u;
        __syncthreads();
    }
    int excl = tsum[t] - s;
    rnk[base] = excl;
    rnk[base + 1] = excl + a0;
    rnk[base + 2] = excl + a0 + a1;
    rnk[base + 3] = excl + a0 + a1 + a2;
    __syncthreads();
    for (int i = t; i < N_EP; i += 1024) {
        int c = rnk[lab[i]];
        ws_cl[i] = c;
        out_lji[i] = (float)c;
        float2 p = ep[i];
        atomicAdd(&cnt[c], 1.f);
        atomicAdd(&sx[c], p.x);
        atomicAdd(&sy[c], p.y);
        atomicAdd(&ss[c], ws_ls[i >> 1]);
    }
}

// K4: junction positions/scores = segment mean
__global__ void k_junc(const float* __restrict__ cnt, const float* __restrict__ sx,
                       const float* __restrict__ sy, const float* __restrict__ ss,
                       float* __restrict__ junc, float* __restrict__ out_pts,
                       float* __restrict__ out_sc) {
    int j = blockIdx.x * 256 + threadIdx.x;
    if (j >= N_EP) return;
    float c = fmaxf(cnt[j], 1.f);
    float jx = sx[j] / c, jy = sy[j] / c;
    junc[2 * j] = jx; junc[2 * j + 1] = jy;
    out_pts[2 * j] = jx; out_pts[2 * j + 1] = jy;
    out_sc[j] = ss[j] / c;
}

// K5: new_lines = junctions[clusters]
__global__ void k_newlines(const int* __restrict__ cl, const float* __restrict__ junc,
                           float* __restrict__ out_nl) {
    int e = blockIdx.x * 256 + threadIdx.x;
    if (e >= N_EP) return;
    int c = cl[e];
    out_nl[2 * e] = junc[2 * c];
    out_nl[2 * e + 1] = junc[2 * c + 1];
}

// K6: keypoint suppression near endpoints. One BLOCK per keypoint;
// 256 threads split the endpoint scan, block-OR reduce.
__global__ __launch_bounds__(256) void k_kp(const float2* __restrict__ ep,
                                            const float2* __restrict__ kpts,
                                            const float* __restrict__ ksc,
                                            int* __restrict__ keep_ws,
                                            float* __restrict__ out_pts,
                                            float* __restrict__ out_sc) {
    __shared__ int s_hit;
    int k = blockIdx.x;
    if (threadIdx.x == 0) s_hit = 0;
    __syncthreads();
    float2 p = kpts[k];
    int hit = 0;
    for (int j = threadIdx.x; j < N_EP; j += 256) {
        float2 q = ep[j];
        float dx = p.x - q.x, dy = p.y - q.y;
        if (dx * dx + dy * dy < 16.0f) hit = 1;
    }
    if (__any(hit) && (threadIdx.x & 63) == 0) atomicOr(&s_hit, 1);
    __syncthreads();
    int keep = !s_hit;
    if (threadIdx.x == 0) {
        keep_ws[k] = keep;
        out_pts[2 * (N_EP + k)] = keep ? p.x : 0.f;
        out_pts[2 * (N_EP + k) + 1] = keep ? p.y : 0.f;
        out_sc[N_EP + k] = keep ? ksc[k] : 0.f;
    }
}

// K7: bilinear sample + L2-normalize junction descriptors. block=junction, thread=channel
__global__ __launch_bounds__(256) void k_sample(const float* __restrict__ ad,
                                                const float* __restrict__ junc,
                                                float* __restrict__ out_desc) {
    int m = blockIdx.x;
    int c = threadIdx.x;
    float px = junc[2 * m], py = junc[2 * m + 1];
    float gx = (px - 4.0f + 0.5f) / 1019.5f * 2.f - 1.f;
    float gy = (py - 4.0f + 0.5f) / 1019.5f * 2.f - 1.f;
    float x = (gx + 1.f) * 0.5f * (WC_ - 1);
    float y = (gy + 1.f) * 0.5f * (HC_ - 1);
    float x0f = fminf(fmaxf(floorf(x), 0.f), WC_ - 1);
    float y0f = fminf(fmaxf(floorf(y), 0.f), HC_ - 1);
    float x1f = fminf(x0f + 1.f, WC_ - 1);
    float y1f = fminf(y0f + 1.f, HC_ - 1);
    float wx = x - x0f, wy = y - y0f;
    int x0 = (int)x0f, x1 = (int)x1f, y0 = (int)y0f, y1 = (int)y1f;
    const float* dch = ad + c * (HC_ * WC_);
    float v = dch[y0 * WC_ + x0] * (1.f - wx) * (1.f - wy)
            + dch[y0 * WC_ + x1] * wx * (1.f - wy)
            + dch[y1 * WC_ + x0] * (1.f - wx) * wy
            + dch[y1 * WC_ + x1] * wx * wy;
    float sq = v * v;
    for (int off = 32; off > 0; off >>= 1) sq += __shfl_down(sq, off);
    __shared__ float wsum[4];
    if ((c & 63) == 0) wsum[c >> 6] = sq;
    __syncthreads();
    float tot = wsum[0] + wsum[1] + wsum[2] + wsum[3];
    float inv = 1.f / fmaxf(sqrtf(tot), 1e-12f);
    out_desc[c * NPTS_ALL + m] = v * inv;
}

// K8: masked copy of keypoint descriptors into concatenated output
__global__ void k_kdesc(const float* __restrict__ desc, const int* __restrict__ keep,
                        float* __restrict__ out_desc) {
    int idx = blockIdx.x * 256 + threadIdx.x;
    if (idx >= CCH * KPTS) return;
    int c = idx >> 11, k = idx & 2047;
    out_desc[c * NPTS_ALL + N_EP + k] = keep[k] ? desc[idx] : 0.f;
}

extern "C" void kernel_launch(void* const* d_in, const int* in_sizes, int n_in,
                              void* d_out, int out_size, void* d_ws, size_t ws_size,
                              hipStream_t stream) {
    const float* lines    = (const float*)d_in[0];   // (1,2048,2,2) == endpoints (4096,2)
    const float* lscores  = (const float*)d_in[1];   // (1,2048)
    const float* kpts     = (const float*)d_in[2];   // (1,2048,2)
    const float* kscores  = (const float*)d_in[3];   // (1,2048)
    const float* descs    = (const float*)d_in[4];   // (1,256,2048)
    const float* alldesc  = (const float*)d_in[5];   // (1,256,128,128)
    float* out = (float*)d_out;

    float* wf = (float*)d_ws;
    int*   wi = (int*)d_ws;

    float* ws_ls  = wf + W_LS;
    int*   deg    = wi + W_DEG;
    int*   nbr    = wi + W_NBR;
    int*   ws_cl  = wi + W_CL;
    float* cnt    = wf + W_CNT;
    float* sx     = wf + W_SX;
    float* sy     = wf + W_SY;
    float* ss     = wf + W_SS;
    float* junc   = wf + W_JUNC;
    int*   keep   = wi + W_KEEP;

    k_ls<<<1, 256, 0, stream>>>(lscores, ws_ls, out + O_LS);
    k_nbr<<<N_EP, 256, 0, stream>>>((const float2*)lines, deg, nbr);
    k_cluster<<<1, 1024, 0, stream>>>((const float2*)lines, deg, nbr, ws_ls, ws_cl,
                                      cnt, sx, sy, ss, out + O_LJI);
    k_junc<<<N_EP / 256, 256, 0, stream>>>(cnt, sx, sy, ss, junc, out + O_PTS,
                                           out + O_SC);
    k_newlines<<<N_EP / 256, 256, 0, stream>>>(ws_cl, junc, out + O_NL);
    k_kp<<<KPTS, 256, 0, stream>>>((const float2*)lines, (const float2*)kpts,
                                   kscores, keep, out + O_PTS, out + O_SC);
    k_sample<<<N_EP, 256, 0, stream>>>(alldesc, junc, out + O_DESC);
    k_kdesc<<<(CCH * KPTS) / 256, 256, 0, stream>>>(descs, keep, out + O_DESC);
}

// Round 3
// 73.718 us; speedup vs baseline: 12.5991x; 1.2140x over previous
//
#include <hip/hip_runtime.h>

#define N_EP     4096     // 2048 lines * 2 endpoints
#define NLINES   2048
#define KPTS     2048
#define CCH      256
#define HC_      128
#define WC_      128
#define MAXNBR   16
#define NPTS_ALL 6144     // N_EP + KPTS

// ---- output chunk offsets (floats) ----
#define O_PTS  0          // all_points (1,6144,2)       12288
#define O_SC   12288      // all_scores (1,6144)          6144
#define O_DESC 18432      // all_descs (1,256,6144)    1572864
#define O_NL   1591296    // new_lines (1,2048,2,2)       8192
#define O_LJI  1599488    // lines_junc_idx (1,2048,2)    4096
#define O_LS   1603584    // ls (1,2048)                  2048

// ---- ws offsets (4-byte words) ----
#define W_LS   0          // float[2048]
#define W_DEG  2048       // int[4096]
#define W_NBR  6144       // int[4096*16]
#define W_CL   71680      // int[4096]
#define W_CNT  75776      // float[4096]
#define W_SX   79872      // float[4096]
#define W_SY   83968      // float[4096]
#define W_SS   88064      // float[4096]
#define W_JUNC 92160      // float[8192] (x,y interleaved)
#define W_KEEP 100352     // int[2048]
#define W_NORM 102400     // float[4096]  sum of squares per junction
#define W_V    106496     // float[256*4096] unnormalized junction descs

// K1: ls = line_scores / (1e-8 + max(line_scores))
__global__ void k_ls(const float* __restrict__ lsc, float* __restrict__ ws_ls,
                     float* __restrict__ out_ls) {
    __shared__ float red[256];
    int t = threadIdx.x;
    float m = -1e30f;
    for (int i = t; i < NLINES; i += 256) m = fmaxf(m, lsc[i]);
    red[t] = m; __syncthreads();
    for (int s = 128; s > 0; s >>= 1) {
        if (t < s) red[t] = fmaxf(red[t], red[t + s]);
        __syncthreads();
    }
    float denom = 1e-8f + red[0];
    for (int i = t; i < NLINES; i += 256) {
        float v = lsc[i] / denom;
        ws_ls[i] = v;
        out_ls[i] = v;
    }
}

// K2: neighbor lists of the eps<=3 ball graph. One BLOCK per point i;
// 256 threads split the 4096-candidate scan. Order in nbr[] is arbitrary
// (atomic append) — min-label propagation is order-invariant.
__global__ __launch_bounds__(256) void k_nbr(const float2* __restrict__ ep,
                                             int* __restrict__ deg,
                                             int* __restrict__ nbr) {
    __shared__ int cnt_s;
    int i = blockIdx.x;
    if (threadIdx.x == 0) cnt_s = 0;
    __syncthreads();
    float2 p = ep[i];
    for (int j = threadIdx.x; j < N_EP; j += 256) {
        if (j == i) continue;
        float2 q = ep[j];
        float dx = p.x - q.x, dy = p.y - q.y;
        if (dx * dx + dy * dy <= 9.0f) {
            int s = atomicAdd(&cnt_s, 1);
            if (s < MAXNBR) nbr[i * MAXNBR + s] = j;
        }
    }
    __syncthreads();
    if (threadIdx.x == 0) deg[i] = min(cnt_s, MAXNBR);
}

// K3: connected-component min-label + dense rank + segment sums
__global__ __launch_bounds__(1024) void k_cluster(
    const float2* __restrict__ ep, const int* __restrict__ deg,
    const int* __restrict__ nbr, const float* __restrict__ ws_ls,
    int* __restrict__ ws_cl, float* __restrict__ cnt, float* __restrict__ sx,
    float* __restrict__ sy, float* __restrict__ ss, float* __restrict__ out_lji) {
    __shared__ int lab[N_EP];
    __shared__ int rnk[N_EP];
    __shared__ int tsum[1024];
    __shared__ int changed;
    int t = threadIdx.x;
    for (int i = t; i < N_EP; i += 1024) {
        cnt[i] = 0.f; sx[i] = 0.f; sy[i] = 0.f; ss[i] = 0.f;
        lab[i] = i;
    }
    // min-label propagation with pointer jumping; fixed point = per-component min index
    for (int it = 0; it < 64; ++it) {
        __syncthreads();
        if (t == 0) changed = 0;
        __syncthreads();
        int f = 0;
        for (int i = t; i < N_EP; i += 1024) {
            int m = lab[i];
            int dg = deg[i];
            const int* nb = nbr + i * MAXNBR;
            for (int q = 0; q < dg; q++) m = min(m, lab[nb[q]]);
            m = min(m, lab[m]);       // pointer jump (lab[k] <= k invariant)
            if (m < lab[i]) { lab[i] = m; f = 1; }
        }
        if (f) atomicOr(&changed, 1);
        __syncthreads();
        if (changed == 0) break;
    }
    __syncthreads();
    // dense rank of root indices (exclusive prefix sum of presence bitmap)
    for (int i = t; i < N_EP; i += 1024) rnk[i] = 0;
    __syncthreads();
    for (int i = t; i < N_EP; i += 1024) rnk[lab[i]] = 1;
    __syncthreads();
    int base = t * 4;
    int a0 = rnk[base], a1 = rnk[base + 1], a2 = rnk[base + 2], a3 = rnk[base + 3];
    int s = a0 + a1 + a2 + a3;
    tsum[t] = s; __syncthreads();
    for (int off = 1; off < 1024; off <<= 1) {
        int v = tsum[t];
        int u = (t >= off) ? tsum[t - off] : 0;
        __syncthreads();
        tsum[t] = v + u;
        __syncthreads();
    }
    int excl = tsum[t] - s;
    rnk[base] = excl;
    rnk[base + 1] = excl + a0;
    rnk[base + 2] = excl + a0 + a1;
    rnk[base + 3] = excl + a0 + a1 + a2;
    __syncthreads();
    for (int i = t; i < N_EP; i += 1024) {
        int c = rnk[lab[i]];
        ws_cl[i] = c;
        out_lji[i] = (float)c;
        float2 p = ep[i];
        atomicAdd(&cnt[c], 1.f);
        atomicAdd(&sx[c], p.x);
        atomicAdd(&sy[c], p.y);
        atomicAdd(&ss[c], ws_ls[i >> 1]);
    }
}

// K4: junction positions/scores = segment mean; also zero the norm accumulator
__global__ void k_junc(const float* __restrict__ cnt, const float* __restrict__ sx,
                       const float* __restrict__ sy, const float* __restrict__ ss,
                       float* __restrict__ junc, float* __restrict__ out_pts,
                       float* __restrict__ out_sc, float* __restrict__ norm) {
    int j = blockIdx.x * 256 + threadIdx.x;
    if (j >= N_EP) return;
    float c = fmaxf(cnt[j], 1.f);
    float jx = sx[j] / c, jy = sy[j] / c;
    junc[2 * j] = jx; junc[2 * j + 1] = jy;
    out_pts[2 * j] = jx; out_pts[2 * j + 1] = jy;
    out_sc[j] = ss[j] / c;
    norm[j] = 0.f;
}

// K5: new_lines = junctions[clusters]
__global__ void k_newlines(const int* __restrict__ cl, const float* __restrict__ junc,
                           float* __restrict__ out_nl) {
    int e = blockIdx.x * 256 + threadIdx.x;
    if (e >= N_EP) return;
    int c = cl[e];
    out_nl[2 * e] = junc[2 * c];
    out_nl[2 * e + 1] = junc[2 * c + 1];
}

// K6: keypoint suppression near endpoints. One BLOCK per keypoint.
__global__ __launch_bounds__(256) void k_kp(const float2* __restrict__ ep,
                                            const float2* __restrict__ kpts,
                                            const float* __restrict__ ksc,
                                            int* __restrict__ keep_ws,
                                            float* __restrict__ out_pts,
                                            float* __restrict__ out_sc) {
    __shared__ int s_hit;
    int k = blockIdx.x;
    if (threadIdx.x == 0) s_hit = 0;
    __syncthreads();
    float2 p = kpts[k];
    int hit = 0;
    for (int j = threadIdx.x; j < N_EP; j += 256) {
        float2 q = ep[j];
        float dx = p.x - q.x, dy = p.y - q.y;
        if (dx * dx + dy * dy < 16.0f) hit = 1;
    }
    if (__any(hit) && (threadIdx.x & 63) == 0) atomicOr(&s_hit, 1);
    __syncthreads();
    int keep = !s_hit;
    if (threadIdx.x == 0) {
        keep_ws[k] = keep;
        out_pts[2 * (N_EP + k)] = keep ? p.x : 0.f;
        out_pts[2 * (N_EP + k) + 1] = keep ? p.y : 0.f;
        out_sc[N_EP + k] = keep ? ksc[k] : 0.f;
    }
}

// K7a: bilinear sample, channel-major. One BLOCK per channel: stage the whole
// 128x128 plane in LDS (64 KB, coalesced float4 loads — input read exactly
// once), then all 4096 junctions sample from LDS. Writes unnormalized v to ws
// (coalesced) and accumulates per-junction sum-of-squares via global atomics.
__global__ __launch_bounds__(256) void k_samp1(const float* __restrict__ ad,
                                               const float* __restrict__ junc,
                                               float* __restrict__ v_ws,
                                               float* __restrict__ norm) {
    __shared__ float plane[HC_ * WC_];   // 64 KB
    int c = blockIdx.x;
    const float4* s4 = (const float4*)(ad + c * (HC_ * WC_));
    float4* p4 = (float4*)plane;
    #pragma unroll 4
    for (int i = threadIdx.x; i < HC_ * WC_ / 4; i += 256) p4[i] = s4[i];
    __syncthreads();
    for (int m = threadIdx.x; m < N_EP; m += 256) {
        float px = junc[2 * m], py = junc[2 * m + 1];
        float gx = (px - 3.5f) / 1019.5f * 2.f - 1.f;
        float gy = (py - 3.5f) / 1019.5f * 2.f - 1.f;
        float x = (gx + 1.f) * 0.5f * (WC_ - 1);
        float y = (gy + 1.f) * 0.5f * (HC_ - 1);
        float x0f = fminf(fmaxf(floorf(x), 0.f), WC_ - 1);
        float y0f = fminf(fmaxf(floorf(y), 0.f), HC_ - 1);
        float x1f = fminf(x0f + 1.f, WC_ - 1);
        float y1f = fminf(y0f + 1.f, HC_ - 1);
        float wx = x - x0f, wy = y - y0f;
        int x0 = (int)x0f, x1 = (int)x1f, y0 = (int)y0f, y1 = (int)y1f;
        float v = plane[y0 * WC_ + x0] * (1.f - wx) * (1.f - wy)
                + plane[y0 * WC_ + x1] * wx * (1.f - wy)
                + plane[y1 * WC_ + x0] * (1.f - wx) * wy
                + plane[y1 * WC_ + x1] * wx * wy;
        v_ws[c * N_EP + m] = v;
        atomicAdd(&norm[m], v * v);
    }
}

// K7b: normalize and write junction descriptors (coalesced along m)
__global__ void k_samp2(const float* __restrict__ v_ws, const float* __restrict__ norm,
                        float* __restrict__ out_desc) {
    int idx = blockIdx.x * 256 + threadIdx.x;   // c*4096 + m
    int c = idx >> 12, m = idx & 4095;
    float inv = 1.f / fmaxf(sqrtf(norm[m]), 1e-12f);
    out_desc[c * NPTS_ALL + m] = v_ws[idx] * inv;
}

// K8: masked copy of keypoint descriptors into concatenated output
__global__ void k_kdesc(const float* __restrict__ desc, const int* __restrict__ keep,
                        float* __restrict__ out_desc) {
    int idx = blockIdx.x * 256 + threadIdx.x;
    if (idx >= CCH * KPTS) return;
    int c = idx >> 11, k = idx & 2047;
    out_desc[c * NPTS_ALL + N_EP + k] = keep[k] ? desc[idx] : 0.f;
}

extern "C" void kernel_launch(void* const* d_in, const int* in_sizes, int n_in,
                              void* d_out, int out_size, void* d_ws, size_t ws_size,
                              hipStream_t stream) {
    const float* lines    = (const float*)d_in[0];   // (1,2048,2,2) == endpoints (4096,2)
    const float* lscores  = (const float*)d_in[1];   // (1,2048)
    const float* kpts     = (const float*)d_in[2];   // (1,2048,2)
    const float* kscores  = (const float*)d_in[3];   // (1,2048)
    const float* descs    = (const float*)d_in[4];   // (1,256,2048)
    const float* alldesc  = (const float*)d_in[5];   // (1,256,128,128)
    float* out = (float*)d_out;

    float* wf = (float*)d_ws;
    int*   wi = (int*)d_ws;

    float* ws_ls  = wf + W_LS;
    int*   deg    = wi + W_DEG;
    int*   nbr    = wi + W_NBR;
    int*   ws_cl  = wi + W_CL;
    float* cnt    = wf + W_CNT;
    float* sx     = wf + W_SX;
    float* sy     = wf + W_SY;
    float* ss     = wf + W_SS;
    float* junc   = wf + W_JUNC;
    int*   keep   = wi + W_KEEP;
    float* norm   = wf + W_NORM;
    float* v_ws   = wf + W_V;

    k_ls<<<1, 256, 0, stream>>>(lscores, ws_ls, out + O_LS);
    k_nbr<<<N_EP, 256, 0, stream>>>((const float2*)lines, deg, nbr);
    k_cluster<<<1, 1024, 0, stream>>>((const float2*)lines, deg, nbr, ws_ls, ws_cl,
                                      cnt, sx, sy, ss, out + O_LJI);
    k_junc<<<N_EP / 256, 256, 0, stream>>>(cnt, sx, sy, ss, junc, out + O_PTS,
                                           out + O_SC, norm);
    k_newlines<<<N_EP / 256, 256, 0, stream>>>(ws_cl, junc, out + O_NL);
    k_kp<<<KPTS, 256, 0, stream>>>((const float2*)lines, (const float2*)kpts,
                                   kscores, keep, out + O_PTS, out + O_SC);
    k_samp1<<<CCH, 256, 0, stream>>>(alldesc, junc, v_ws, norm);
    k_samp2<<<(CCH * N_EP) / 256, 256, 0, stream>>>(v_ws, norm, out + O_DESC);
    k_kdesc<<<(CCH * KPTS) / 256, 256, 0, stream>>>(descs, keep, out + O_DESC);
}